// Round 6
// baseline (217.563 us; speedup 1.0000x reference)
//
#include <hip/hip_runtime.h>

// LongConvBlock, round 11: main compute loop restructured from 1-D A-sharing
// (1A+4B reads per 4 MFMAs = 1.25) to 2-D Toeplitz sharing: wave owns
// CONSECUTIVE si quad {4w..4w+3}, betas processed in PAIRS; per chunk:
// 2 A-frags + 5 consecutive X strips feed 8 MFMAs (0.875 reads/MFMA, -30%
// DS reads). Main measured at 93% of its DS-read throughput floor (64us),
// so DS-read count is the only remaining lever. Consecutive strips are
// +256-short immediate offsets (XOR ^b unaffected by +32-block steps).
// Per-acc beta order stays ascending. Wave load imbalance is fine: DS pipe
// is CU-aggregate with 12 resident waves.
// prep: round-8. untranspose: round-9. oarea aliased into xs (round-10).
//
// out[b,l,h] = sum_j x[b,j,h] * k'[h,l-j],  k'[0] += D[h].

typedef __attribute__((ext_vector_type(8)))  short s16x8;   // 8 bf16
typedef __attribute__((ext_vector_type(16))) float f32x16;  // 32x32 acc
typedef __attribute__((ext_vector_type(4)))  float f32x4;
typedef __attribute__((ext_vector_type(4)))  unsigned int u32x4;

constexpr int B_ = 4, L_ = 4096, H_ = 1024;
constexpr int PADX = 256;
constexpr int LX = L_ + PADX;    // 4352 xT row
constexpr int LK = L_ + 32;      // 4128 kR row (= 8*516)
constexpr int ST = 256;          // outputs per (wave, si)
constexpr int NST = L_ / ST;     // 16

constexpr size_t XT_ELEMS = (size_t)B_ * H_ * LX;
constexpr size_t KR_ELEMS = (size_t)2 * H_ * LK;
constexpr size_t OT_ELEMS = (size_t)B_ * H_ * L_;
constexpr size_t WS_NEEDED = (XT_ELEMS + KR_ELEMS + OT_ELEMS) * sizeof(unsigned short);

constexpr int XS_ROW  = 4320;           // x window per b (l in [-224,4095])
constexpr int XS_BLKS = XS_ROW / 8;     // 540
constexpr int XS_US   = B_ * XS_ROW;    // 17280
constexpr int KS_US   = 2 * LK;         // 8256
constexpr int OAREA_DW = 4 * 132;       // 528 dwords per wave (aliased into xs)
constexpr int SMEM_MAIN = XS_US * 2 + KS_US * 2;   // 51072 B -> 3 blocks/CU

constexpr int nHt = H_ / 64, nLt = L_ / 64;
constexpr int NXB = B_ * nLt * nHt;     // 4096 x-tile blocks in prep
constexpr int nLt2 = L_ / 128;
constexpr int NUT = B_ * nLt2 * nHt;    // 2048 untranspose blocks (64h x 128l)

__device__ __forceinline__ unsigned short f2bf(float f) {
    unsigned int u = __builtin_bit_cast(unsigned int, f);
    u += 0x7fffu + ((u >> 16) & 1u);    // RTNE
    return (unsigned short)(u >> 16);
}
__device__ __forceinline__ float bf2f(unsigned short u) {
    return __builtin_bit_cast(float, (unsigned int)u << 16);
}
__device__ __forceinline__ unsigned int sw16(unsigned int x) {
    return (x >> 16) | (x << 16);
}

// ---- prep (fused): x -> xT bf16 transposed (+left pad), k -> kR reversed ----
__global__ __launch_bounds__(256)
void prep(const float* __restrict__ x, const float* __restrict__ kin,
          const float* __restrict__ Dk,
          unsigned short* __restrict__ xT, unsigned short* __restrict__ kR)
{
    __shared__ __align__(16) unsigned char pshm[16704];   // union: tile / kb0+kb1
    const int bid = blockIdx.x;
    if (bid < NXB) {
        float (*tile)[65] = (float (*)[65])pshm;          // 64x65 f32 = 16640 B
        const int b  = bid / (nLt * nHt);
        const int r0 = bid % (nLt * nHt);
        const int l0 = (r0 / nHt) * 64;
        const int h0 = (r0 % nHt) * 64;
        const int j  = threadIdx.x;
        const int h4 = j & 15;            // h quad
        const int rg = j >> 4;            // row group
        #pragma unroll
        for (int it = 0; it < 4; ++it) {
            const int lr = rg + 16 * it;
            const f32x4 v = *(const f32x4*)(x + ((size_t)b * L_ + l0 + lr) * H_ + h0 + 4 * h4);
            tile[lr][4 * h4 + 0] = v.x; tile[lr][4 * h4 + 1] = v.y;
            tile[lr][4 * h4 + 2] = v.z; tile[lr][4 * h4 + 3] = v.w;
        }
        __syncthreads();
        const int lg = j & 7;             // 8-element l group
        #pragma unroll
        for (int pp = 0; pp < 2; ++pp) {
            const int hh = (j >> 3) + 32 * pp;
            unsigned int w0 = (unsigned int)f2bf(tile[8*lg+0][hh]) | ((unsigned int)f2bf(tile[8*lg+1][hh]) << 16);
            unsigned int w1 = (unsigned int)f2bf(tile[8*lg+2][hh]) | ((unsigned int)f2bf(tile[8*lg+3][hh]) << 16);
            unsigned int w2 = (unsigned int)f2bf(tile[8*lg+4][hh]) | ((unsigned int)f2bf(tile[8*lg+5][hh]) << 16);
            unsigned int w3 = (unsigned int)f2bf(tile[8*lg+6][hh]) | ((unsigned int)f2bf(tile[8*lg+7][hh]) << 16);
            const u32x4 v = {w0, w1, w2, w3};
            *(u32x4*)(xT + ((size_t)b * H_ + h0 + hh) * LX + PADX + l0 + 8 * lg) = v;
        }
        if (l0 == 0) {                    // left pad [0, PADX) zeros
            #pragma unroll
            for (int it = 0; it < 8; ++it) {
                const int idx = j + 256 * it;         // 2048 vec-blocks
                const int row = idx >> 5, off = idx & 31;
                const u32x4 z = {};
                *(u32x4*)(xT + ((size_t)b * H_ + h0 + row) * LX + off * 8) = z;
            }
        }
    } else {
        unsigned short* kb0 = (unsigned short*)pshm;          // [4144]; k'(l) at 40+l
        unsigned short* kb1 = kb0 + 4144;                     // [4144]; k'(l) at 41+l
        const int h = bid - NXB;
        const int j = threadIdx.x;
        const float Dv = Dk[h];
        if (j < 40) { kb0[j] = 0; kb1[j] = 0; }               // heads
        // compute 17 values l in [16j-1, 16j+15]
        const float* kh = kin + (size_t)h * L_;
        float vv[17];
        {
            const int l0 = 16 * j;
            float am = (j > 0) ? kh[l0 - 1] : 0.0f;
            vv[0] = copysignf(fmaxf(fabsf(am) - 0.1f, 0.0f), am);
            #pragma unroll
            for (int g = 0; g < 4; ++g) {
                const f32x4 a = *(const f32x4*)(kh + l0 + 4 * g);
                vv[1 + 4*g + 0] = copysignf(fmaxf(fabsf(a.x) - 0.1f, 0.0f), a.x);
                vv[1 + 4*g + 1] = copysignf(fmaxf(fabsf(a.y) - 0.1f, 0.0f), a.y);
                vv[1 + 4*g + 2] = copysignf(fmaxf(fabsf(a.z) - 0.1f, 0.0f), a.z);
                vv[1 + 4*g + 3] = copysignf(fmaxf(fabsf(a.w) - 0.1f, 0.0f), a.w);
            }
            if (j == 0) vv[1] += Dv;                          // l == 0
        }
        {
            unsigned int d0[8], d1[8];
            #pragma unroll
            for (int g = 0; g < 8; ++g) {
                d0[g] = (unsigned int)f2bf(vv[1 + 2*g]) | ((unsigned int)f2bf(vv[2 + 2*g]) << 16);
                d1[g] = (unsigned int)f2bf(vv[0 + 2*g]) | ((unsigned int)f2bf(vv[1 + 2*g]) << 16);
            }
            u32x4* p0 = (u32x4*)(kb0 + 40 + 16 * j);
            u32x4* p1 = (u32x4*)(kb1 + 40 + 16 * j);
            p0[0] = u32x4{d0[0], d0[1], d0[2], d0[3]};
            p0[1] = u32x4{d0[4], d0[5], d0[6], d0[7]};
            p1[0] = u32x4{d1[0], d1[1], d1[2], d1[3]};
            p1[1] = u32x4{d1[4], d1[5], d1[6], d1[7]};
        }
        __syncthreads();
        // reversed vector stores: 516 octets per parity row
        for (int v = j; v < LK / 8; v += 256) {
            const u32x4 a0 = *(const u32x4*)(kb0 + 4128 - 8 * v);
            const u32x4 a1 = *(const u32x4*)(kb1 + 4128 - 8 * v);
            const u32x4 r0 = {sw16(a0.w), sw16(a0.z), sw16(a0.y), sw16(a0.x)};
            const u32x4 r1 = {sw16(a1.w), sw16(a1.z), sw16(a1.y), sw16(a1.x)};
            *(u32x4*)(kR + (size_t)h * LK + 8 * v) = r0;
            *(u32x4*)(kR + ((size_t)H_ + h) * LK + 8 * v) = r1;
        }
    }
}

#define MFMA_BF16 __builtin_amdgcn_mfma_f32_32x32x16_bf16

// ---- main ----
__global__ __launch_bounds__(256, 2)
void longconv_main(const unsigned short* __restrict__ xT,
                   const unsigned short* __restrict__ kR,
                   unsigned int* __restrict__ outT)   // out_tmp packed bf16 pairs
{
    __shared__ __align__(16) unsigned char smem[SMEM_MAIN];
    unsigned short* xs = (unsigned short*)smem;
    unsigned short* ks = (unsigned short*)(smem + (size_t)XS_US * 2);

    const int h   = blockIdx.x;
    const int tid = threadIdx.x;

    // stage in: x window (b-XOR swizzled 16B blocks) + k band (2 parity copies)
    constexpr int NXU = XS_BLKS * 4;          // 2160
    constexpr int NKU = 2 * (LK / 8);         // 1032
    for (int u = tid; u < NXU + NKU; u += 256) {
        if (u < NXU) {
            const int b = u / XS_BLKS, n = u - b * XS_BLKS;
            const u32x4 v = *(const u32x4*)(xT + ((size_t)b * H_ + h) * LX + 32 + n * 8);
            *(u32x4*)(xs + (size_t)b * XS_ROW + (size_t)(n ^ b) * 8) = v;
        } else {
            const int v2 = u - NXU;
            const int p = v2 / (LK / 8), i = v2 - p * (LK / 8);
            const u32x4 v = *(const u32x4*)(kR + ((size_t)p * H_ + h) * LK + i * 8);
            *(u32x4*)(ks + (size_t)p * LK + (size_t)i * 8) = v;
        }
    }
    __syncthreads();

    const int w  = tid >> 6, ln = tid & 63;
    const int m  = ln & 31,  q  = ln >> 5;
    const int t  = m >> 2,   b  = m & 3;

    // A: frag(r)[j] = ks[p][(base-p) + r + j],  base = 3871 - m + 8q, p = base&1
    const int base = 3871 - m + 8 * q;
    const int p    = base & 1;
    const unsigned int* abase = (const unsigned int*)(ks + p * LK + (base - p));
    const unsigned short* xrow = xs + (size_t)b * XS_ROW;
    const int nb = 4 * t + q;

    // X strip anchors (strip 0, both chunk parities). Strip n = anchor + n*256
    // shorts: adding 32 blocks never interacts with the ^b swizzle (low 2 bits).
    const unsigned short* X0a = xrow + (size_t)(((nb + 0) ^ b) * 8);
    const unsigned short* X0b = xrow + (size_t)(((nb + 2) ^ b) * 8);

    f32x16 acc0 = {}, acc1 = {}, acc2 = {}, acc3 = {};

    // ---- super-bodies: betas (0,1),(2,3),...,(4w-2,4w-1); quad si {4w+d} ----
    // chunk i: A(beta), A(beta+1) + X strips n0..n0+4 (n0 = 4w-1-beta) feed
    // 8 MFMAs: acc_d += A(b)*X_{d+1}; acc_d += A(b+1)*X_d   (beta asc per acc)
    const unsigned short* sXa = X0a + (4 * w - 1) * 256;
    const unsigned short* sXb = X0b + (4 * w - 1) * 256;
    for (int sb = 0; sb < 2 * w; ++sb) {
        const unsigned int* abaseP = abase - 128;   // A(beta+1)
        #pragma unroll
        for (int i = 0; i < 16; ++i) {
            u32x4 a0, a1;
            a0.x = abase[8*i+0];  a0.y = abase[8*i+1];
            a0.z = abase[8*i+2];  a0.w = abase[8*i+3];
            a1.x = abaseP[8*i+0]; a1.y = abaseP[8*i+1];
            a1.z = abaseP[8*i+2]; a1.w = abaseP[8*i+3];
            const s16x8 af0 = __builtin_bit_cast(s16x8, a0);
            const s16x8 af1 = __builtin_bit_cast(s16x8, a1);
            const unsigned short* xp = ((i & 1) ? sXb : sXa) + 32 * (i >> 1);
            const s16x8 x0 = *(const s16x8*)(xp);
            const s16x8 x1 = *(const s16x8*)(xp + 256);
            const s16x8 x2 = *(const s16x8*)(xp + 512);
            const s16x8 x3 = *(const s16x8*)(xp + 768);
            const s16x8 x4 = *(const s16x8*)(xp + 1024);
            acc0 = MFMA_BF16(af0, x1, acc0, 0,0,0);
            acc0 = MFMA_BF16(af1, x0, acc0, 0,0,0);
            acc1 = MFMA_BF16(af0, x2, acc1, 0,0,0);
            acc1 = MFMA_BF16(af1, x1, acc1, 0,0,0);
            acc2 = MFMA_BF16(af0, x3, acc2, 0,0,0);
            acc2 = MFMA_BF16(af1, x2, acc2, 0,0,0);
            acc3 = MFMA_BF16(af0, x4, acc3, 0,0,0);
            acc3 = MFMA_BF16(af1, x3, acc3, 0,0,0);
        }
        abase -= 256; sXa -= 512; sXb -= 512;
    }

    // ---- tails: betas 4w+e, e=0..3; active d >= e; X strip (d-e) ----
#define TAILBODY(D0, D1, D2, D3, O0, O1, O2, O3)                            \
  {                                                                         \
    _Pragma("unroll")                                                       \
    for (int i = 0; i < 16; ++i) {                                          \
      u32x4 aw;                                                             \
      aw.x = abase[8*i+0]; aw.y = abase[8*i+1];                             \
      aw.z = abase[8*i+2]; aw.w = abase[8*i+3];                             \
      const s16x8 af = __builtin_bit_cast(s16x8, aw);                       \
      const unsigned short* xp = ((i & 1) ? X0b : X0a) + 32 * (i >> 1);     \
      if (D0) acc0 = MFMA_BF16(af, *(const s16x8*)(xp + O0), acc0, 0,0,0);  \
      if (D1) acc1 = MFMA_BF16(af, *(const s16x8*)(xp + O1), acc1, 0,0,0);  \
      if (D2) acc2 = MFMA_BF16(af, *(const s16x8*)(xp + O2), acc2, 0,0,0);  \
      if (D3) acc3 = MFMA_BF16(af, *(const s16x8*)(xp + O3), acc3, 0,0,0);  \
    }                                                                       \
    abase -= 128;                                                           \
  }
    TAILBODY(1, 1, 1, 1, 0, 256, 512, 768);   // beta = 4w
    TAILBODY(0, 1, 1, 1, 0, 0,   256, 512);   // beta = 4w+1
    TAILBODY(0, 0, 1, 1, 0, 0,   0,   256);   // beta = 4w+2
    TAILBODY(0, 0, 0, 1, 0, 0,   0,   0  );   // beta = 4w+3
#undef TAILBODY

    // ---- stage out via per-wave LDS area, ALIASED into xs (dead now) ----
    __syncthreads();                       // all waves done with xs/ks reads
    float* oarea = (float*)smem;
    float* ar = oarea + w * OAREA_DW;
    auto writeout = [&](const f32x16& acc, int si) {
        const int Ls = si * ST;
        #pragma unroll
        for (int rh = 0; rh < 2; ++rh) {
            #pragma unroll
            for (int rr2 = 0; rr2 < 2; ++rr2) {
                const int base4 = (8 * rr2 + 4 * q + 4 * t) & 15;
                f32x4 qd;
                qd.x = acc[4 * (2 * rh + rr2) + 0];
                qd.y = acc[4 * (2 * rh + rr2) + 1];
                qd.z = acc[4 * (2 * rh + rr2) + 2];
                qd.w = acc[4 * (2 * rh + rr2) + 3];
                *(f32x4*)(ar + b * 132 + 16 * t + base4) = qd;
            }
            __asm__ volatile("s_waitcnt lgkmcnt(0)" ::: "memory");
            #pragma unroll
            for (int bb = 0; bb < 4; ++bb) {
                const int g  = ln >> 3;
                const int uu = (2 * ln) & 15;
                const int s  = (uu + 4 * g) & 15;
                const float v0 = ar[bb * 132 + 16 * g + s];
                const float v1 = ar[bb * 132 + 16 * g + s + 1];
                const int l = 32 * g + 16 * rh + uu;
                const unsigned int pk =
                    (unsigned int)f2bf(v0) | ((unsigned int)f2bf(v1) << 16);
                outT[(((size_t)bb * H_ + h) * L_ + Ls + l) >> 1] = pk;
            }
            __asm__ volatile("s_waitcnt lgkmcnt(0)" ::: "memory");
        }
    };
    writeout(acc0, 4 * w + 0);
    writeout(acc1, 4 * w + 1);
    writeout(acc2, 4 * w + 2);
    writeout(acc3, 4 * w + 3);
}

// ---- out_tmp bf16 [B][H][L] -> out f32 [B][L][H], 64h x 128l per block ----
__global__ __launch_bounds__(256)
void untranspose(const unsigned short* __restrict__ outT, float* __restrict__ out)
{
    __shared__ __align__(16) float tile[128][68];
    const int bid = blockIdx.x;
    const int b  = bid / (nLt2 * nHt);
    const int r0 = bid % (nLt2 * nHt);
    const int l0 = (r0 / nHt) * 128;
    const int h0 = (r0 % nHt) * 64;
    const int j  = threadIdx.x;
    const int lg = j & 7;
    u32x4 v[2][2];
    #pragma unroll
    for (int tt = 0; tt < 2; ++tt)
        #pragma unroll
        for (int pp = 0; pp < 2; ++pp) {
            const int hh = (j >> 3) + 32 * pp;
            v[tt][pp] = *(const u32x4*)(outT + ((size_t)b * H_ + h0 + hh) * L_
                                        + l0 + 64 * tt + 8 * lg);
        }
    #pragma unroll
    for (int tt = 0; tt < 2; ++tt)
        #pragma unroll
        for (int pp = 0; pp < 2; ++pp) {
            const int hh = (j >> 3) + 32 * pp;
            const unsigned short* pu = (const unsigned short*)&v[tt][pp];
            #pragma unroll
            for (int i = 0; i < 8; ++i) {
                const int row = 64 * tt + 8 * lg + i;   // (row>>3)&7 == lg
                tile[row][hh ^ (4 * lg)] = bf2f(pu[i]);
            }
        }
    __syncthreads();
    const int hg = j & 15;
    #pragma unroll
    for (int pz = 0; pz < 8; ++pz) {
        const int ll = (j >> 4) + 16 * pz;              // l index 0..127
        const f32x4 vv = *(const f32x4*)(&tile[ll][4 * (hg ^ ((ll >> 3) & 7))]);
        *(f32x4*)(out + ((size_t)b * L_ + l0 + ll) * H_ + h0 + 4 * hg) = vv;
    }
}

// ---- fallback: fp32 direct conv (only if ws too small) ----
constexpr int TLf = 32, Uf = 8, Wf = TLf + Uf - 1, HTf = 256;

__global__ __launch_bounds__(HTf)
void longconv_fp32(const float* __restrict__ x, const float* __restrict__ k,
                   const float* __restrict__ Dskip, float* __restrict__ out)
{
    const int h  = blockIdx.y * HTf + threadIdx.x;
    const int b  = blockIdx.z;
    const int lt = (int)gridDim.x - 1 - (int)blockIdx.x;
    const int L0 = lt * TLf;
    const float* __restrict__ xb = x + ((size_t)b * L_) * H_ + h;
    const float* __restrict__ kh = k + (size_t)h * L_;
    float acc[TLf]; float win[Wf];
    #pragma unroll
    for (int i = 0; i < Wf; ++i) {
        const int idx = L0 - (Uf - 1) + i;
        win[i] = (idx >= 0) ? xb[(size_t)idx * H_] : 0.0f;
    }
    const float Dv = Dskip[h];
    #pragma unroll
    for (int jj = 0; jj < TLf; ++jj) acc[jj] = win[jj + Uf - 1] * Dv;
    const int cmax = L0 / Uf + (TLf / Uf) - 1;
    for (int c = 0; c <= cmax; ++c) {
        float kr[Uf];
        #pragma unroll
        for (int u = 0; u < Uf; ++u) {
            const float a = kh[c * Uf + u];
            kr[u] = copysignf(fmaxf(fabsf(a) - 0.1f, 0.0f), a);
        }
        #pragma unroll
        for (int u = 0; u < Uf; ++u)
            #pragma unroll
            for (int jj = 0; jj < TLf; ++jj)
                acc[jj] = fmaf(kr[u], win[jj + (Uf - 1) - u], acc[jj]);
        if (c < cmax) {
            #pragma unroll
            for (int i = Wf - 1; i >= Uf; --i) win[i] = win[i - Uf];
            #pragma unroll
            for (int i = 0; i < Uf; ++i) {
                const int idx = L0 - (c + 1) * Uf - (Uf - 1) + i;
                win[i] = (idx >= 0) ? xb[(size_t)idx * H_] : 0.0f;
            }
        }
    }
    float* __restrict__ ob = out + ((size_t)b * L_ + L0) * H_ + h;
    #pragma unroll
    for (int jj = 0; jj < TLf; ++jj) ob[(size_t)jj * H_] = acc[jj];
}

extern "C" void kernel_launch(void* const* d_in, const int* in_sizes, int n_in,
                              void* d_out, int out_size, void* d_ws, size_t ws_size,
                              hipStream_t stream)
{
    const float* x  = (const float*)d_in[0];   // [B, L, H]
    const float* k  = (const float*)d_in[1];   // [1, H, L]
    const float* Dk = (const float*)d_in[2];   // [1, H]
    float* out = (float*)d_out;                // [B, L, H]

    if (ws_size >= WS_NEEDED) {
        unsigned short* xT = (unsigned short*)d_ws;
        unsigned short* kR = xT + XT_ELEMS;
        unsigned short* oT = kR + KR_ELEMS;
        prep<<<dim3(NXB + H_), dim3(256), 0, stream>>>(x, k, Dk, xT, kR);
        longconv_main<<<dim3(H_), dim3(256), 0, stream>>>(xT, kR, (unsigned int*)oT);
        untranspose<<<dim3(NUT), dim3(256), 0, stream>>>(oT, out);
    } else {
        dim3 grid(L_ / TLf, H_ / HTf, B_);
        longconv_fp32<<<grid, dim3(HTf), 0, stream>>>(x, k, Dk, out);
    }
}

// Round 7
// 208.386 us; speedup vs baseline: 1.0440x; 1.0440x over previous
//
#include <hip/hip_runtime.h>

// LongConvBlock, round 12: main = 2-D Toeplitz sharing with BALANCED pair
// assignment. Wave w owns pairs (2w,2w+1) and (14-2w,15-2w) -> exactly 544
// MFMA/wave (r11's contiguous quads put 928 on SIMD3 vs 160 on SIMD0: MFMA
// pipe is per-SIMD -> critical path). Beta processed in PAIRS per pair:
// chunk = 2 A frags + 3 consecutive X strips -> 8 MFMAs (block DS reads
// 3104 -> 2432, -22%). Source-interleaved per pair (<=3 X live) to avoid
// r11's spill (it loaded 5 strips up front -> VGPR 128 + scratch).
// Guards: VGPR<=110, FETCH~25.8MB, WRITE~32.8MB, 3 blocks/CU.
// prep: round-8. untranspose: round-9. oarea aliased into xs (round-10).
//
// out[b,l,h] = sum_j x[b,j,h] * k'[h,l-j],  k'[0] += D[h].

typedef __attribute__((ext_vector_type(8)))  short s16x8;   // 8 bf16
typedef __attribute__((ext_vector_type(16))) float f32x16;  // 32x32 acc
typedef __attribute__((ext_vector_type(4)))  float f32x4;
typedef __attribute__((ext_vector_type(4)))  unsigned int u32x4;

constexpr int B_ = 4, L_ = 4096, H_ = 1024;
constexpr int PADX = 256;
constexpr int LX = L_ + PADX;    // 4352 xT row
constexpr int LK = L_ + 32;      // 4128 kR row (= 8*516)
constexpr int ST = 256;          // outputs per (wave, si)
constexpr int NST = L_ / ST;     // 16

constexpr size_t XT_ELEMS = (size_t)B_ * H_ * LX;
constexpr size_t KR_ELEMS = (size_t)2 * H_ * LK;
constexpr size_t OT_ELEMS = (size_t)B_ * H_ * L_;
constexpr size_t WS_NEEDED = (XT_ELEMS + KR_ELEMS + OT_ELEMS) * sizeof(unsigned short);

constexpr int XS_ROW  = 4320;           // x window per b (l in [-224,4095])
constexpr int XS_BLKS = XS_ROW / 8;     // 540
constexpr int XS_US   = B_ * XS_ROW;    // 17280
constexpr int KS_US   = 2 * LK;         // 8256
constexpr int OAREA_DW = 4 * 132;       // 528 dwords per wave (aliased into xs)
constexpr int SMEM_MAIN = XS_US * 2 + KS_US * 2;   // 51072 B -> 3 blocks/CU

constexpr int nHt = H_ / 64, nLt = L_ / 64;
constexpr int NXB = B_ * nLt * nHt;     // 4096 x-tile blocks in prep
constexpr int nLt2 = L_ / 128;
constexpr int NUT = B_ * nLt2 * nHt;    // 2048 untranspose blocks (64h x 128l)

__device__ __forceinline__ unsigned short f2bf(float f) {
    unsigned int u = __builtin_bit_cast(unsigned int, f);
    u += 0x7fffu + ((u >> 16) & 1u);    // RTNE
    return (unsigned short)(u >> 16);
}
__device__ __forceinline__ float bf2f(unsigned short u) {
    return __builtin_bit_cast(float, (unsigned int)u << 16);
}
__device__ __forceinline__ unsigned int sw16(unsigned int x) {
    return (x >> 16) | (x << 16);
}

// ---- prep (fused): x -> xT bf16 transposed (+left pad), k -> kR reversed ----
__global__ __launch_bounds__(256)
void prep(const float* __restrict__ x, const float* __restrict__ kin,
          const float* __restrict__ Dk,
          unsigned short* __restrict__ xT, unsigned short* __restrict__ kR)
{
    __shared__ __align__(16) unsigned char pshm[16704];   // union: tile / kb0+kb1
    const int bid = blockIdx.x;
    if (bid < NXB) {
        float (*tile)[65] = (float (*)[65])pshm;          // 64x65 f32 = 16640 B
        const int b  = bid / (nLt * nHt);
        const int r0 = bid % (nLt * nHt);
        const int l0 = (r0 / nHt) * 64;
        const int h0 = (r0 % nHt) * 64;
        const int j  = threadIdx.x;
        const int h4 = j & 15;            // h quad
        const int rg = j >> 4;            // row group
        #pragma unroll
        for (int it = 0; it < 4; ++it) {
            const int lr = rg + 16 * it;
            const f32x4 v = *(const f32x4*)(x + ((size_t)b * L_ + l0 + lr) * H_ + h0 + 4 * h4);
            tile[lr][4 * h4 + 0] = v.x; tile[lr][4 * h4 + 1] = v.y;
            tile[lr][4 * h4 + 2] = v.z; tile[lr][4 * h4 + 3] = v.w;
        }
        __syncthreads();
        const int lg = j & 7;             // 8-element l group
        #pragma unroll
        for (int pp = 0; pp < 2; ++pp) {
            const int hh = (j >> 3) + 32 * pp;
            unsigned int w0 = (unsigned int)f2bf(tile[8*lg+0][hh]) | ((unsigned int)f2bf(tile[8*lg+1][hh]) << 16);
            unsigned int w1 = (unsigned int)f2bf(tile[8*lg+2][hh]) | ((unsigned int)f2bf(tile[8*lg+3][hh]) << 16);
            unsigned int w2 = (unsigned int)f2bf(tile[8*lg+4][hh]) | ((unsigned int)f2bf(tile[8*lg+5][hh]) << 16);
            unsigned int w3 = (unsigned int)f2bf(tile[8*lg+6][hh]) | ((unsigned int)f2bf(tile[8*lg+7][hh]) << 16);
            const u32x4 v = {w0, w1, w2, w3};
            *(u32x4*)(xT + ((size_t)b * H_ + h0 + hh) * LX + PADX + l0 + 8 * lg) = v;
        }
        if (l0 == 0) {                    // left pad [0, PADX) zeros
            #pragma unroll
            for (int it = 0; it < 8; ++it) {
                const int idx = j + 256 * it;         // 2048 vec-blocks
                const int row = idx >> 5, off = idx & 31;
                const u32x4 z = {};
                *(u32x4*)(xT + ((size_t)b * H_ + h0 + row) * LX + off * 8) = z;
            }
        }
    } else {
        unsigned short* kb0 = (unsigned short*)pshm;          // [4144]; k'(l) at 40+l
        unsigned short* kb1 = kb0 + 4144;                     // [4144]; k'(l) at 41+l
        const int h = bid - NXB;
        const int j = threadIdx.x;
        const float Dv = Dk[h];
        if (j < 40) { kb0[j] = 0; kb1[j] = 0; }               // heads
        // compute 17 values l in [16j-1, 16j+15]
        const float* kh = kin + (size_t)h * L_;
        float vv[17];
        {
            const int l0 = 16 * j;
            float am = (j > 0) ? kh[l0 - 1] : 0.0f;
            vv[0] = copysignf(fmaxf(fabsf(am) - 0.1f, 0.0f), am);
            #pragma unroll
            for (int g = 0; g < 4; ++g) {
                const f32x4 a = *(const f32x4*)(kh + l0 + 4 * g);
                vv[1 + 4*g + 0] = copysignf(fmaxf(fabsf(a.x) - 0.1f, 0.0f), a.x);
                vv[1 + 4*g + 1] = copysignf(fmaxf(fabsf(a.y) - 0.1f, 0.0f), a.y);
                vv[1 + 4*g + 2] = copysignf(fmaxf(fabsf(a.z) - 0.1f, 0.0f), a.z);
                vv[1 + 4*g + 3] = copysignf(fmaxf(fabsf(a.w) - 0.1f, 0.0f), a.w);
            }
            if (j == 0) vv[1] += Dv;                          // l == 0
        }
        {
            unsigned int d0[8], d1[8];
            #pragma unroll
            for (int g = 0; g < 8; ++g) {
                d0[g] = (unsigned int)f2bf(vv[1 + 2*g]) | ((unsigned int)f2bf(vv[2 + 2*g]) << 16);
                d1[g] = (unsigned int)f2bf(vv[0 + 2*g]) | ((unsigned int)f2bf(vv[1 + 2*g]) << 16);
            }
            u32x4* p0 = (u32x4*)(kb0 + 40 + 16 * j);
            u32x4* p1 = (u32x4*)(kb1 + 40 + 16 * j);
            p0[0] = u32x4{d0[0], d0[1], d0[2], d0[3]};
            p0[1] = u32x4{d0[4], d0[5], d0[6], d0[7]};
            p1[0] = u32x4{d1[0], d1[1], d1[2], d1[3]};
            p1[1] = u32x4{d1[4], d1[5], d1[6], d1[7]};
        }
        __syncthreads();
        // reversed vector stores: 516 octets per parity row
        for (int v = j; v < LK / 8; v += 256) {
            const u32x4 a0 = *(const u32x4*)(kb0 + 4128 - 8 * v);
            const u32x4 a1 = *(const u32x4*)(kb1 + 4128 - 8 * v);
            const u32x4 r0 = {sw16(a0.w), sw16(a0.z), sw16(a0.y), sw16(a0.x)};
            const u32x4 r1 = {sw16(a1.w), sw16(a1.z), sw16(a1.y), sw16(a1.x)};
            *(u32x4*)(kR + (size_t)h * LK + 8 * v) = r0;
            *(u32x4*)(kR + ((size_t)H_ + h) * LK + 8 * v) = r1;
        }
    }
}

#define MFMA_BF16 __builtin_amdgcn_mfma_f32_32x32x16_bf16

// Super-body: beta pair (beta0, beta0+1). Per chunk i: A(beta0), A(beta0+1)
// + per active pair 3 consecutive X strips -> 8 MFMAs (full) / 2 strips ->
// 3 MFMAs (final). P#F = pair# full, P#L = pair# final. Pair phases are
// source-sequential so <=3 X strips live at a time (anti-spill).
#define SBODY(P1F, P1L, P2F, P2L)                                            \
  {                                                                          \
    const unsigned int* ab1 = abase - 128;                                   \
    _Pragma("unroll")                                                        \
    for (int i = 0; i < 16; ++i) {                                           \
      u32x4 a0, a1;                                                          \
      a0.x = abase[8*i+0]; a0.y = abase[8*i+1];                              \
      a0.z = abase[8*i+2]; a0.w = abase[8*i+3];                              \
      a1.x = ab1[8*i+0];   a1.y = ab1[8*i+1];                                \
      a1.z = ab1[8*i+2];   a1.w = ab1[8*i+3];                                \
      const s16x8 af0 = __builtin_bit_cast(s16x8, a0);                       \
      const s16x8 af1 = __builtin_bit_cast(s16x8, a1);                       \
      const int io = 32 * (i >> 1);                                          \
      if (P1F) {                                                             \
        const unsigned short* xp = ((i & 1) ? p1b : p1a) + io;               \
        const s16x8 x0 = *(const s16x8*)(xp);                                \
        const s16x8 x1 = *(const s16x8*)(xp + 256);                          \
        const s16x8 x2 = *(const s16x8*)(xp + 512);                          \
        accL1 = MFMA_BF16(af0, x1, accL1, 0,0,0);                            \
        accH1 = MFMA_BF16(af0, x2, accH1, 0,0,0);                            \
        accL1 = MFMA_BF16(af1, x0, accL1, 0,0,0);                            \
        accH1 = MFMA_BF16(af1, x1, accH1, 0,0,0);                            \
      }                                                                      \
      if (P1L) {                                                             \
        const unsigned short* xp = ((i & 1) ? X0b : X0a) + io;               \
        const s16x8 x0 = *(const s16x8*)(xp);                                \
        const s16x8 x1 = *(const s16x8*)(xp + 256);                          \
        accL1 = MFMA_BF16(af0, x0, accL1, 0,0,0);                            \
        accH1 = MFMA_BF16(af0, x1, accH1, 0,0,0);                            \
        accH1 = MFMA_BF16(af1, x0, accH1, 0,0,0);                            \
      }                                                                      \
      if (P2F) {                                                             \
        const unsigned short* xp = ((i & 1) ? p2b : p2a) + io;               \
        const s16x8 x0 = *(const s16x8*)(xp);                                \
        const s16x8 x1 = *(const s16x8*)(xp + 256);                          \
        const s16x8 x2 = *(const s16x8*)(xp + 512);                          \
        accL2 = MFMA_BF16(af0, x1, accL2, 0,0,0);                            \
        accH2 = MFMA_BF16(af0, x2, accH2, 0,0,0);                            \
        accL2 = MFMA_BF16(af1, x0, accL2, 0,0,0);                            \
        accH2 = MFMA_BF16(af1, x1, accH2, 0,0,0);                            \
      }                                                                      \
      if (P2L) {                                                             \
        const unsigned short* xp = ((i & 1) ? X0b : X0a) + io;               \
        const s16x8 x0 = *(const s16x8*)(xp);                                \
        const s16x8 x1 = *(const s16x8*)(xp + 256);                          \
        accL2 = MFMA_BF16(af0, x0, accL2, 0,0,0);                            \
        accH2 = MFMA_BF16(af0, x1, accH2, 0,0,0);                            \
        accH2 = MFMA_BF16(af1, x0, accH2, 0,0,0);                            \
      }                                                                      \
    }                                                                        \
    abase -= 256;                                                            \
    if (P1F) { p1a -= 512; p1b -= 512; }                                     \
    if (P2F) { p2a -= 512; p2b -= 512; }                                     \
  }

// ---- main ----
__global__ __launch_bounds__(256, 2)
void longconv_main(const unsigned short* __restrict__ xT,
                   const unsigned short* __restrict__ kR,
                   unsigned int* __restrict__ outT)   // out_tmp packed bf16 pairs
{
    __shared__ __align__(16) unsigned char smem[SMEM_MAIN];
    unsigned short* xs = (unsigned short*)smem;
    unsigned short* ks = (unsigned short*)(smem + (size_t)XS_US * 2);

    const int h   = blockIdx.x;
    const int tid = threadIdx.x;

    // stage in: x window (b-XOR swizzled 16B blocks) + k band (2 parity copies)
    constexpr int NXU = XS_BLKS * 4;          // 2160
    constexpr int NKU = 2 * (LK / 8);         // 1032
    for (int u = tid; u < NXU + NKU; u += 256) {
        if (u < NXU) {
            const int b = u / XS_BLKS, n = u - b * XS_BLKS;
            const u32x4 v = *(const u32x4*)(xT + ((size_t)b * H_ + h) * LX + 32 + n * 8);
            *(u32x4*)(xs + (size_t)b * XS_ROW + (size_t)(n ^ b) * 8) = v;
        } else {
            const int v2 = u - NXU;
            const int p = v2 / (LK / 8), i = v2 - p * (LK / 8);
            const u32x4 v = *(const u32x4*)(kR + ((size_t)p * H_ + h) * LK + i * 8);
            *(u32x4*)(ks + (size_t)p * LK + (size_t)i * 8) = v;
        }
    }
    __syncthreads();

    const int w  = tid >> 6, ln = tid & 63;
    const int m  = ln & 31,  q  = ln >> 5;
    const int t  = m >> 2,   b  = m & 3;
    const int s1 = 2 * w;            // pair1 = (s1, s1+1)
    const int s2 = 14 - 2 * w;       // pair2 = (s2, s2+1); 544 MFMA/wave

    // A: frag(r)[j] = ks[p][(base-p) + r + j],  base = 3871 - m + 8q, p = base&1
    const int base = 3871 - m + 8 * q;
    const int p    = base & 1;
    const unsigned int* abase = (const unsigned int*)(ks + p * LK + (base - p));
    const unsigned short* xrow = xs + (size_t)b * XS_ROW;
    const int nb = 4 * t + q;

    // X strip anchors (strip 0, both chunk parities). Strip n = anchor + n*256
    // shorts (+32 blocks: never touches the ^b swizzle low bits).
    const unsigned short* X0a = xrow + (size_t)(((nb + 0) ^ b) * 8);
    const unsigned short* X0b = xrow + (size_t)(((nb + 2) ^ b) * 8);

    // Pair track pointers start at strip (s-1); full SB reads +0,+256,+512
    // (strips s-1-beta0, s-beta0, s+1-beta0), decrement 2 strips per SB.
    const unsigned short* p1a = X0a + (s1 - 1) * 256;
    const unsigned short* p1b = X0b + (s1 - 1) * 256;
    const unsigned short* p2a = X0a + (s2 - 1) * 256;
    const unsigned short* p2b = X0b + (s2 - 1) * 256;

    f32x16 accL1 = {}, accH1 = {}, accL2 = {}, accH2 = {};

    // SB k has beta0 = 2k.  k<w: both pairs full; k==w: pair1 final + pair2
    // full; w<k<7-w: pair2 full; k==7-w: pair2 final.  (beta ascending/acc.)
    for (int k = 0; k < w; ++k) SBODY(1, 0, 1, 0);
    SBODY(0, 1, 1, 0);
    for (int k = w + 1; k < 7 - w; ++k) SBODY(0, 0, 1, 0);
    SBODY(0, 0, 0, 1);

    // ---- stage out via per-wave LDS area, ALIASED into xs (dead now) ----
    __syncthreads();                       // all waves done with xs/ks reads
    float* oarea = (float*)smem;
    float* ar = oarea + w * OAREA_DW;
    auto writeout = [&](const f32x16& acc, int si) {
        const int Ls = si * ST;
        #pragma unroll
        for (int rh = 0; rh < 2; ++rh) {
            #pragma unroll
            for (int rr2 = 0; rr2 < 2; ++rr2) {
                const int base4 = (8 * rr2 + 4 * q + 4 * t) & 15;
                f32x4 qd;
                qd.x = acc[4 * (2 * rh + rr2) + 0];
                qd.y = acc[4 * (2 * rh + rr2) + 1];
                qd.z = acc[4 * (2 * rh + rr2) + 2];
                qd.w = acc[4 * (2 * rh + rr2) + 3];
                *(f32x4*)(ar + b * 132 + 16 * t + base4) = qd;
            }
            __asm__ volatile("s_waitcnt lgkmcnt(0)" ::: "memory");
            #pragma unroll
            for (int bb = 0; bb < 4; ++bb) {
                const int g  = ln >> 3;
                const int uu = (2 * ln) & 15;
                const int s  = (uu + 4 * g) & 15;
                const float v0 = ar[bb * 132 + 16 * g + s];
                const float v1 = ar[bb * 132 + 16 * g + s + 1];
                const int l = 32 * g + 16 * rh + uu;
                const unsigned int pk =
                    (unsigned int)f2bf(v0) | ((unsigned int)f2bf(v1) << 16);
                outT[(((size_t)bb * H_ + h) * L_ + Ls + l) >> 1] = pk;
            }
            __asm__ volatile("s_waitcnt lgkmcnt(0)" ::: "memory");
        }
    };
    writeout(accL1, s1);
    writeout(accH1, s1 + 1);
    writeout(accL2, s2);
    writeout(accH2, s2 + 1);
}

// ---- out_tmp bf16 [B][H][L] -> out f32 [B][L][H], 64h x 128l per block ----
__global__ __launch_bounds__(256)
void untranspose(const unsigned short* __restrict__ outT, float* __restrict__ out)
{
    __shared__ __align__(16) float tile[128][68];
    const int bid = blockIdx.x;
    const int b  = bid / (nLt2 * nHt);
    const int r0 = bid % (nLt2 * nHt);
    const int l0 = (r0 / nHt) * 128;
    const int h0 = (r0 % nHt) * 64;
    const int j  = threadIdx.x;
    const int lg = j & 7;
    u32x4 v[2][2];
    #pragma unroll
    for (int tt = 0; tt < 2; ++tt)
        #pragma unroll
        for (int pp = 0; pp < 2; ++pp) {
            const int hh = (j >> 3) + 32 * pp;
            v[tt][pp] = *(const u32x4*)(outT + ((size_t)b * H_ + h0 + hh) * L_
                                        + l0 + 64 * tt + 8 * lg);
        }
    #pragma unroll
    for (int tt = 0; tt < 2; ++tt)
        #pragma unroll
        for (int pp = 0; pp < 2; ++pp) {
            const int hh = (j >> 3) + 32 * pp;
            const unsigned short* pu = (const unsigned short*)&v[tt][pp];
            #pragma unroll
            for (int i = 0; i < 8; ++i) {
                const int row = 64 * tt + 8 * lg + i;   // (row>>3)&7 == lg
                tile[row][hh ^ (4 * lg)] = bf2f(pu[i]);
            }
        }
    __syncthreads();
    const int hg = j & 15;
    #pragma unroll
    for (int pz = 0; pz < 8; ++pz) {
        const int ll = (j >> 4) + 16 * pz;              // l index 0..127
        const f32x4 vv = *(const f32x4*)(&tile[ll][4 * (hg ^ ((ll >> 3) & 7))]);
        *(f32x4*)(out + ((size_t)b * L_ + l0 + ll) * H_ + h0 + 4 * hg) = vv;
    }
}

// ---- fallback: fp32 direct conv (only if ws too small) ----
constexpr int TLf = 32, Uf = 8, Wf = TLf + Uf - 1, HTf = 256;

__global__ __launch_bounds__(HTf)
void longconv_fp32(const float* __restrict__ x, const float* __restrict__ k,
                   const float* __restrict__ Dskip, float* __restrict__ out)
{
    const int h  = blockIdx.y * HTf + threadIdx.x;
    const int b  = blockIdx.z;
    const int lt = (int)gridDim.x - 1 - (int)blockIdx.x;
    const int L0 = lt * TLf;
    const float* __restrict__ xb = x + ((size_t)b * L_) * H_ + h;
    const float* __restrict__ kh = k + (size_t)h * L_;
    float acc[TLf]; float win[Wf];
    #pragma unroll
    for (int i = 0; i < Wf; ++i) {
        const int idx = L0 - (Uf - 1) + i;
        win[i] = (idx >= 0) ? xb[(size_t)idx * H_] : 0.0f;
    }
    const float Dv = Dskip[h];
    #pragma unroll
    for (int jj = 0; jj < TLf; ++jj) acc[jj] = win[jj + Uf - 1] * Dv;
    const int cmax = L0 / Uf + (TLf / Uf) - 1;
    for (int c = 0; c <= cmax; ++c) {
        float kr[Uf];
        #pragma unroll
        for (int u = 0; u < Uf; ++u) {
            const float a = kh[c * Uf + u];
            kr[u] = copysignf(fmaxf(fabsf(a) - 0.1f, 0.0f), a);
        }
        #pragma unroll
        for (int u = 0; u < Uf; ++u)
            #pragma unroll
            for (int jj = 0; jj < TLf; ++jj)
                acc[jj] = fmaf(kr[u], win[jj + (Uf - 1) - u], acc[jj]);
        if (c < cmax) {
            #pragma unroll
            for (int i = Wf - 1; i >= Uf; --i) win[i] = win[i - Uf];
            #pragma unroll
            for (int i = 0; i < Uf; ++i) {
                const int idx = L0 - (c + 1) * Uf - (Uf - 1) + i;
                win[i] = (idx >= 0) ? xb[(size_t)idx * H_] : 0.0f;
            }
        }
    }
    float* __restrict__ ob = out + ((size_t)b * L_ + L0) * H_ + h;
    #pragma unroll
    for (int jj = 0; jj < TLf; ++jj) ob[(size_t)jj * H_] = acc[jj];
}

extern "C" void kernel_launch(void* const* d_in, const int* in_sizes, int n_in,
                              void* d_out, int out_size, void* d_ws, size_t ws_size,
                              hipStream_t stream)
{
    const float* x  = (const float*)d_in[0];   // [B, L, H]
    const float* k  = (const float*)d_in[1];   // [1, H, L]
    const float* Dk = (const float*)d_in[2];   // [1, H]
    float* out = (float*)d_out;                // [B, L, H]

    if (ws_size >= WS_NEEDED) {
        unsigned short* xT = (unsigned short*)d_ws;
        unsigned short* kR = xT + XT_ELEMS;
        unsigned short* oT = kR + KR_ELEMS;
        prep<<<dim3(NXB + H_), dim3(256), 0, stream>>>(x, k, Dk, xT, kR);
        longconv_main<<<dim3(H_), dim3(256), 0, stream>>>(xT, kR, (unsigned int*)oT);
        untranspose<<<dim3(NUT), dim3(256), 0, stream>>>(oT, out);
    } else {
        dim3 grid(L_ / TLf, H_ / HTf, B_);
        longconv_fp32<<<grid, dim3(HTf), 0, stream>>>(x, k, Dk, out);
    }
}